// Round 1
// baseline (637.763 us; speedup 1.0000x reference)
//
#include <hip/hip_runtime.h>
#include <hip/hip_bf16.h>
#include <math.h>

#define NB 2048
#define NS 512
#define ND 96
#define SH_STRIDE 112  // padded row stride (shorts): rows 0..3 of a quad hit disjoint bank octets

typedef __attribute__((ext_vector_type(8))) short short8;
typedef __attribute__((ext_vector_type(4))) float floatx4;

__device__ __forceinline__ short f2bf(float f) {
    union { float f; unsigned u; } c; c.f = f;
    unsigned u = c.u;
    u += 0x7FFF + ((u >> 16) & 1);   // RNE
    return (short)(u >> 16);
}
__device__ __forceinline__ float bf2f(short s) {
    union { unsigned u; float f; } c;
    c.u = ((unsigned)(unsigned short)s) << 16;
    return c.f;
}

__global__ __launch_bounds__(256, 1)
void attn_fused(const float* __restrict__ seq,   // (B,S,96)
                const float* __restrict__ tgt,   // (B,1,96)
                const int*   __restrict__ mask,  // (B,513,1) as int32
                const float* __restrict__ w1,    // (96,96) [e][d]
                const float* __restrict__ b1,    // (96)
                const float* __restrict__ w2,    // (96,96) [e][d]
                const float* __restrict__ b2,    // (96)
                float* __restrict__ out)         // (B,96)
{
    __shared__ short sh[NS * SH_STRIDE];   // seq_h in bf16, ~112 KB
    __shared__ float sc_lds[NS];
    __shared__ float attn[NS];
    __shared__ float tgt_h[ND];
    __shared__ float red[8];
    __shared__ float osum[2][ND];

    const int b    = blockIdx.x;
    const int tid  = threadIdx.x;
    const int lane = tid & 63;
    const int wave = tid >> 6;
    const int l15  = lane & 15;
    const int quad = lane >> 4;

    // ---- tgt_h[e] = dot(tgt[b], w2[e,:]) + b2[e]  (full fp32) ----
    if (tid < ND) {
        const float* tv = tgt + (size_t)b * ND;
        const float* wr = w2 + tid * ND;
        float acc = b2[tid];
        #pragma unroll
        for (int d = 0; d < ND; d += 4) {
            acc += tv[d]*wr[d] + tv[d+1]*wr[d+1] + tv[d+2]*wr[d+2] + tv[d+3]*wr[d+3];
        }
        tgt_h[tid] = acc;
    }

    // ---- preload W1 B-fragments (bf16) + bias; B[k=quad*8+j][n=l15] = w1[e][d] ----
    short8 bfrag[6][3];
    float biasv[6];
    #pragma unroll
    for (int t = 0; t < 6; ++t) {
        const int e = 16 * t + l15;
        biasv[t] = b1[e];
        #pragma unroll
        for (int kk = 0; kk < 3; ++kk) {
            const float* p = w1 + e * ND + kk * 32 + quad * 8;
            floatx4 p0 = *(const floatx4*)(p);
            floatx4 p1 = *(const floatx4*)(p + 4);
            short8 v;
            v[0]=f2bf(p0[0]); v[1]=f2bf(p0[1]); v[2]=f2bf(p0[2]); v[3]=f2bf(p0[3]);
            v[4]=f2bf(p1[0]); v[5]=f2bf(p1[1]); v[6]=f2bf(p1[2]); v[7]=f2bf(p1[3]);
            bfrag[t][kk] = v;
        }
    }

    __syncthreads();   // tgt_h ready

    float tgtv[6];
    #pragma unroll
    for (int t = 0; t < 6; ++t) tgtv[t] = tgt_h[16 * t + l15];

    // A-fragment base: lane reads seq[b, s0+l15, kk*32 + quad*8 .. +8]
    const float* abase = seq + ((size_t)b * NS + l15) * ND + quad * 8;

    // ---- main loop: each wave owns 8 s-tiles of 16 rows ----
    #pragma unroll
    for (int sti = 0; sti < 8; ++sti) {
        const int st = wave * 8 + sti;
        const int s0 = st * 16;
        short8 af[3];
        #pragma unroll
        for (int kk = 0; kk < 3; ++kk) {
            const float* p = abase + (size_t)s0 * ND + kk * 32;
            floatx4 p0 = *(const floatx4*)(p);
            floatx4 p1 = *(const floatx4*)(p + 4);
            short8 v;
            v[0]=f2bf(p0[0]); v[1]=f2bf(p0[1]); v[2]=f2bf(p0[2]); v[3]=f2bf(p0[3]);
            v[4]=f2bf(p1[0]); v[5]=f2bf(p1[1]); v[6]=f2bf(p1[2]); v[7]=f2bf(p1[3]);
            af[kk] = v;
        }
        float part0 = 0.f, part1 = 0.f, part2 = 0.f, part3 = 0.f;
        #pragma unroll
        for (int t = 0; t < 6; ++t) {
            floatx4 acc = { biasv[t], biasv[t], biasv[t], biasv[t] };
            acc = __builtin_amdgcn_mfma_f32_16x16x32_bf16(af[0], bfrag[t][0], acc, 0, 0, 0);
            acc = __builtin_amdgcn_mfma_f32_16x16x32_bf16(af[1], bfrag[t][1], acc, 0, 0, 0);
            acc = __builtin_amdgcn_mfma_f32_16x16x32_bf16(af[2], bfrag[t][2], acc, 0, 0, 0);
            const int e = 16 * t + l15;
            short* dst = &sh[(s0 + quad * 4) * SH_STRIDE + e];
            const float x0 = acc[0], x1 = acc[1], x2 = acc[2], x3 = acc[3];
            dst[0]             = f2bf(x0);
            dst[SH_STRIDE]     = f2bf(x1);
            dst[2 * SH_STRIDE] = f2bf(x2);
            dst[3 * SH_STRIDE] = f2bf(x3);
            const float th = tgtv[t];
            part0 += 1.0f / (1.0f + __expf(-(x0 + th)));
            part1 += 1.0f / (1.0f + __expf(-(x1 + th)));
            part2 += 1.0f / (1.0f + __expf(-(x2 + th)));
            part3 += 1.0f / (1.0f + __expf(-(x3 + th)));
        }
        // reduce score over the 16 lanes of each quad (cols e)
        #pragma unroll
        for (int off = 1; off < 16; off <<= 1) {
            part0 += __shfl_xor(part0, off, 64);
            part1 += __shfl_xor(part1, off, 64);
            part2 += __shfl_xor(part2, off, 64);
            part3 += __shfl_xor(part3, off, 64);
        }
        if (l15 == 0) {
            sc_lds[s0 + quad * 4 + 0] = part0;
            sc_lds[s0 + quad * 4 + 1] = part1;
            sc_lds[s0 + quad * 4 + 2] = part2;
            sc_lds[s0 + quad * 4 + 3] = part3;
        }
    }
    __syncthreads();

    // ---- masked softmax over s (mirror reference: masked -> -1e9, then softmax) ----
    float v0 = sc_lds[tid];
    float v1 = sc_lds[tid + 256];
    if (mask[(size_t)b * (NS + 1) + tid] != 0)       v0 = -1e9f;
    if (mask[(size_t)b * (NS + 1) + tid + 256] != 0) v1 = -1e9f;
    float mx = fmaxf(v0, v1);
    #pragma unroll
    for (int off = 1; off < 64; off <<= 1) mx = fmaxf(mx, __shfl_xor(mx, off, 64));
    if (lane == 0) red[wave] = mx;
    __syncthreads();
    mx = fmaxf(fmaxf(red[0], red[1]), fmaxf(red[2], red[3]));
    const float e0 = __expf(v0 - mx);
    const float e1 = __expf(v1 - mx);
    float ssum = e0 + e1;
    #pragma unroll
    for (int off = 1; off < 64; off <<= 1) ssum += __shfl_xor(ssum, off, 64);
    if (lane == 0) red[4 + wave] = ssum;
    __syncthreads();
    const float inv = 1.0f / (red[4] + red[5] + red[6] + red[7]);
    attn[tid]       = e0 * inv;
    attn[tid + 256] = e1 * inv;
    __syncthreads();

    // ---- output: out[b,e] = sum_s attn[s] * seq_h[s,e] ----
    if (tid < 2 * ND) {
        const int half = tid / ND;          // 0 or 1 (s halves)
        const int e    = tid - half * ND;
        float acc = 0.f;
        const int sb = half * 256;
        #pragma unroll 4
        for (int s = sb; s < sb + 256; ++s) {
            acc += attn[s] * bf2f(sh[s * SH_STRIDE + e]);
        }
        osum[half][e] = acc;
    }
    __syncthreads();
    if (tid < ND) out[(size_t)b * ND + tid] = osum[0][tid] + osum[1][tid];
}

extern "C" void kernel_launch(void* const* d_in, const int* in_sizes, int n_in,
                              void* d_out, int out_size, void* d_ws, size_t ws_size,
                              hipStream_t stream) {
    const float* seq  = (const float*)d_in[0];
    const float* tgt  = (const float*)d_in[1];
    const int*   mask = (const int*)d_in[2];
    const float* w1   = (const float*)d_in[3];
    const float* b1   = (const float*)d_in[4];
    const float* w2   = (const float*)d_in[5];
    const float* b2   = (const float*)d_in[6];
    float* out = (float*)d_out;
    attn_fused<<<dim3(NB), dim3(256), 0, stream>>>(seq, tgt, mask, w1, b1, w2, b2, out);
}

// Round 2
// 589.674 us; speedup vs baseline: 1.0816x; 1.0816x over previous
//
#include <hip/hip_runtime.h>
#include <math.h>

#define NB 2048
#define NS 512
#define ND 96

typedef __attribute__((ext_vector_type(8))) short short8;
typedef __attribute__((ext_vector_type(4))) float floatx4;

__device__ __forceinline__ unsigned f2bfu(float f) {
    union { float f; unsigned u; } c; c.f = f;
    unsigned u = c.u;
    u += 0x7FFF + ((u >> 16) & 1);   // RNE
    return u >> 16;
}
__device__ __forceinline__ unsigned pack2(float a, float b) {
    return f2bfu(a) | (f2bfu(b) << 16);
}
__device__ __forceinline__ float lo_f(unsigned u) {
    union { unsigned u; float f; } c; c.u = u << 16; return c.f;
}
__device__ __forceinline__ float hi_f(unsigned u) {
    union { unsigned u; float f; } c; c.u = u & 0xFFFF0000u; return c.f;
}
__device__ __forceinline__ float sigm(float x) {
    return 1.0f / (1.0f + __expf(-x));
}

__global__ __launch_bounds__(512, 4)
void attn_fused(const float* __restrict__ seq,   // (B,S,96)
                const float* __restrict__ tgt,   // (B,1,96)
                const int*   __restrict__ mask,  // (B,513,1) int32
                const float* __restrict__ w1,    // (96,96) [e][d]
                const float* __restrict__ b1,    // (96)
                const float* __restrict__ w2,    // (96,96) [e][d]
                const float* __restrict__ b2,    // (96)
                float* __restrict__ out)         // (B,96)
{
    // W1 staged as bf16 MFMA B-fragments: frag(t,kk) for lane L at
    // w1f[((t*3+kk)*64 + L)*8 .. +8]  — ds_read_b128, conflict-free.
    __shared__ short w1f[18 * 64 * 8];           // 18 KB
    __shared__ float sc[NS];                     // scores
    __shared__ float at[NS];                     // attn weights
    __shared__ float th[ND];                     // tgt_h
    __shared__ float red1[8], red2[8];
    __shared__ float osum[8][ND];                // per-wave output partials

    const int b    = blockIdx.x;
    const int tid  = threadIdx.x;
    const int lane = tid & 63;
    const int wave = tid >> 6;
    const int l15  = lane & 15;
    const int quad = lane >> 4;

    // ---- stage W1 -> bf16 fragments in LDS ----
    for (int idx = tid; idx < 1152; idx += 512) {   // 96 rows x 12 chunks of 8
        const int e  = idx / 12;
        const int dc = idx - 12 * e;
        const int kk = dc >> 2;
        const int q  = dc & 3;
        const float* p = w1 + e * ND + kk * 32 + q * 8;
        floatx4 p0 = *(const floatx4*)(p);
        floatx4 p1 = *(const floatx4*)(p + 4);
        short8 v;
        v[0]=(short)f2bfu(p0[0]); v[1]=(short)f2bfu(p0[1]);
        v[2]=(short)f2bfu(p0[2]); v[3]=(short)f2bfu(p0[3]);
        v[4]=(short)f2bfu(p1[0]); v[5]=(short)f2bfu(p1[1]);
        v[6]=(short)f2bfu(p1[2]); v[7]=(short)f2bfu(p1[3]);
        const int t = e >> 4, r = e & 15;
        *(short8*)&w1f[(((t * 3 + kk) * 64) + q * 16 + r) * 8] = v;
    }

    // ---- tgt_h[e] = dot(tgt[b], w2[e,:]) + b2[e] (fp32) ----
    if (tid < ND) {
        const float* tv = tgt + (size_t)b * ND;
        const float* wr = w2 + tid * ND;
        float acc = b2[tid];
        #pragma unroll
        for (int d = 0; d < ND; d += 4) {
            acc += tv[d]*wr[d] + tv[d+1]*wr[d+1] + tv[d+2]*wr[d+2] + tv[d+3]*wr[d+3];
        }
        th[tid] = acc;
    }
    __syncthreads();

    float tgtv[6], biasv[6];
    #pragma unroll
    for (int t = 0; t < 6; ++t) {
        tgtv[t]  = th[16 * t + l15];
        biasv[t] = b1[16 * t + l15];
    }

    // ---- main loop: each of 8 waves owns 4 s-tiles of 16 rows ----
    // lane's seq_h kept in packed-bf16 registers: pk[tile][t][0..1]
    unsigned pk[4][6][2];
    const float* abase = seq + ((size_t)b * NS + l15) * ND + quad * 8;

    #pragma unroll
    for (int sti = 0; sti < 4; ++sti) {
        const int s0 = (wave * 4 + sti) * 16;
        short8 af[3];
        #pragma unroll
        for (int kk = 0; kk < 3; ++kk) {
            const float* p = abase + (size_t)s0 * ND + kk * 32;
            floatx4 p0 = *(const floatx4*)(p);
            floatx4 p1 = *(const floatx4*)(p + 4);
            short8 v;
            v[0]=(short)f2bfu(p0[0]); v[1]=(short)f2bfu(p0[1]);
            v[2]=(short)f2bfu(p0[2]); v[3]=(short)f2bfu(p0[3]);
            v[4]=(short)f2bfu(p1[0]); v[5]=(short)f2bfu(p1[1]);
            v[6]=(short)f2bfu(p1[2]); v[7]=(short)f2bfu(p1[3]);
            af[kk] = v;
        }
        float p0s = 0.f, p1s = 0.f, p2s = 0.f, p3s = 0.f;
        #pragma unroll
        for (int t = 0; t < 6; ++t) {
            floatx4 acc = { biasv[t], biasv[t], biasv[t], biasv[t] };
            #pragma unroll
            for (int kk = 0; kk < 3; ++kk) {
                const short8 bf = *(const short8*)&w1f[((t * 3 + kk) * 64 + lane) * 8];
                acc = __builtin_amdgcn_mfma_f32_16x16x32_bf16(af[kk], bf, acc, 0, 0, 0);
            }
            pk[sti][t][0] = pack2(acc[0], acc[1]);
            pk[sti][t][1] = pack2(acc[2], acc[3]);
            const float thv = tgtv[t];
            p0s += sigm(acc[0] + thv);
            p1s += sigm(acc[1] + thv);
            p2s += sigm(acc[2] + thv);
            p3s += sigm(acc[3] + thv);
        }
        // reduce over the 16 lanes (e-columns) of each quad
        #pragma unroll
        for (int off = 1; off < 16; off <<= 1) {
            p0s += __shfl_xor(p0s, off, 64);
            p1s += __shfl_xor(p1s, off, 64);
            p2s += __shfl_xor(p2s, off, 64);
            p3s += __shfl_xor(p3s, off, 64);
        }
        if (l15 == 0) {
            sc[s0 + quad * 4 + 0] = p0s;
            sc[s0 + quad * 4 + 1] = p1s;
            sc[s0 + quad * 4 + 2] = p2s;
            sc[s0 + quad * 4 + 3] = p3s;
        }
    }
    __syncthreads();

    // ---- masked softmax over s (one thread per s) ----
    float v = sc[tid];
    if (mask[(size_t)b * (NS + 1) + tid] != 0) v = -1e9f;
    float mx = v;
    #pragma unroll
    for (int off = 1; off < 64; off <<= 1) mx = fmaxf(mx, __shfl_xor(mx, off, 64));
    if (lane == 0) red1[wave] = mx;
    __syncthreads();
    mx = red1[0];
    #pragma unroll
    for (int w = 1; w < 8; ++w) mx = fmaxf(mx, red1[w]);
    const float e0 = __expf(v - mx);
    float ssum = e0;
    #pragma unroll
    for (int off = 1; off < 64; off <<= 1) ssum += __shfl_xor(ssum, off, 64);
    if (lane == 0) red2[wave] = ssum;
    __syncthreads();
    float tot = red2[0];
    #pragma unroll
    for (int w = 1; w < 8; ++w) tot += red2[w];
    at[tid] = e0 * (1.0f / tot);
    __syncthreads();

    // ---- output: out[b,e] = sum_s attn[s] * seq_h[s,e], register-resident ----
    float o[6] = {0.f, 0.f, 0.f, 0.f, 0.f, 0.f};
    #pragma unroll
    for (int sti = 0; sti < 4; ++sti) {
        const int s0 = (wave * 4 + sti) * 16 + quad * 4;
        const float a0 = at[s0], a1 = at[s0 + 1], a2 = at[s0 + 2], a3 = at[s0 + 3];
        #pragma unroll
        for (int t = 0; t < 6; ++t) {
            const unsigned u0 = pk[sti][t][0];
            const unsigned u1 = pk[sti][t][1];
            o[t] += a0 * lo_f(u0) + a1 * hi_f(u0) + a2 * lo_f(u1) + a3 * hi_f(u1);
        }
    }
    #pragma unroll
    for (int t = 0; t < 6; ++t) {
        o[t] += __shfl_xor(o[t], 16, 64);
        o[t] += __shfl_xor(o[t], 32, 64);
    }
    if (quad == 0) {
        #pragma unroll
        for (int t = 0; t < 6; ++t) osum[wave][16 * t + l15] = o[t];
    }
    __syncthreads();
    if (tid < ND) {
        float a = 0.f;
        #pragma unroll
        for (int w = 0; w < 8; ++w) a += osum[w][tid];
        out[(size_t)b * ND + tid] = a;
    }
}

extern "C" void kernel_launch(void* const* d_in, const int* in_sizes, int n_in,
                              void* d_out, int out_size, void* d_ws, size_t ws_size,
                              hipStream_t stream) {
    const float* seq  = (const float*)d_in[0];
    const float* tgt  = (const float*)d_in[1];
    const int*   mask = (const int*)d_in[2];
    const float* w1   = (const float*)d_in[3];
    const float* b1   = (const float*)d_in[4];
    const float* w2   = (const float*)d_in[5];
    const float* b2   = (const float*)d_in[6];
    float* out = (float*)d_out;
    attn_fused<<<dim3(NB), dim3(512), 0, stream>>>(seq, tgt, mask, w1, b1, w2, b2, out);
}